// Round 9
// baseline (249.252 us; speedup 1.0000x reference)
//
#include <hip/hip_runtime.h>
#include <hip/hip_bf16.h>
#include <math.h>

#define BB 64
#define PP 100
#define NN 1000
#define DD 128
#define HH 8
#define QDQ 16
#define NTOT 1196
#define HALFK 598
#define CH 128
#define QROWS 16
#define LOG2E 1.44269504088896f

// ---------------- Kernel A: q = q_first + x @ Wq^T (inline-transpose LDS GEMM)
__global__ __launch_bounds__(256) void k_qcalc(const float* __restrict__ x,
                                               const float* __restrict__ Wq,
                                               const float* __restrict__ qf,
                                               float* __restrict__ qout) {
  __shared__ float sw[128 * 65];       // W[j][dl] for current d-half, padded
  __shared__ float xs[QROWS * DD];     // 8 KB
  int tid = threadIdx.x;
  int row0 = blockIdx.x * QROWS;

  for (int i = tid; i < QROWS * DD / 4; i += 256)
    ((float4*)xs)[i] = ((const float4*)(x + (size_t)row0 * DD))[i];

  int j = tid & 127, rr = tid >> 7;
  float acc[8];
#pragma unroll
  for (int i = 0; i < 8; ++i) acc[i] = 0.f;

  for (int half = 0; half < 2; ++half) {
    __syncthreads();
    for (int idx = tid; idx < 128 * 64; idx += 256) {
      int jj = idx >> 6, dl = idx & 63;
      sw[jj * 65 + dl] = Wq[jj * DD + half * 64 + dl];   // coalesced row reads
    }
    __syncthreads();
#pragma unroll
    for (int ri = 0; ri < 8; ++ri) {
      int r = 2 * ri + rr;
      float a = acc[ri];
#pragma unroll 16
      for (int dl = 0; dl < 64; ++dl)
        a += xs[r * DD + half * 64 + dl] * sw[j * 65 + dl];
      acc[ri] = a;
    }
  }
#pragma unroll
  for (int ri = 0; ri < 8; ++ri) {
    int bp = row0 + 2 * ri + rr;
    int b = bp / PP, p = bp % PP;
    int h = j >> 4, qd = j & 15;
    size_t qi = ((size_t)(b * HH + h) * PP + p) * QDQ + qd;
    qout[qi] = acc[ri] + qf[qi];
  }
}

// ------- Kernel F: mask -> bf16 table mt[b][n][p'] = mask*log2e - 20 ----------
// p' pair-packs (p, p+64) into one dword: p' = 2*(p&63) + (p>>6)
__global__ __launch_bounds__(256) void k_mask_t(const float* __restrict__ mask,
                                                __hip_bfloat16* __restrict__ mt) {
  __shared__ float tile[64][65];
  int nt = blockIdx.x;           // 19 tiles over n (0..1215, bound NTOT)
  int pt = blockIdx.y;           // 2 tiles over p (0..127)
  int b  = blockIdx.z;
  int tx = threadIdx.x & 63, ty = threadIdx.x >> 6;
  int n0 = nt * 64, p0 = pt * 64;
#pragma unroll
  for (int r = ty; r < 64; r += 4) {
    int p = p0 + r, n = n0 + tx;
    tile[r][tx] = (p < PP && n < NN) ? mask[((size_t)b * PP + p) * NN + n] * LOG2E - 20.f
                                     : -20.f;
  }
  __syncthreads();
#pragma unroll
  for (int r = ty; r < 64; r += 4) {
    int n = n0 + r, p = p0 + tx;
    int pp = ((p & 63) << 1) | (p >> 6);
    if (n < NTOT)
      mt[((size_t)b * NTOT + n) * 128 + pp] = __float2bfloat16(tile[tx][r]);
  }
}

// ---------------- Kernel B: MHA partial — 2q/lane, 2-key unroll, bf16 mask ----
// grid = 1024 (XCD-swizzled: 512 bh * 2 halves); block = 512 (8 waves)
// wave w handles key pairs (i, i+8) of each 128-key chunk; lane owns queries
// (lane, lane+64). Fixed -20 offset baked into mt -> w = exp2(s), sums only.
#define QKDOT(qv, K0, K1, K2, K3) \
  (qv[0] * K0.x + qv[1] * K0.y + qv[2] * K0.z + qv[3] * K0.w \
 + qv[4] * K1.x + qv[5] * K1.y + qv[6] * K1.z + qv[7] * K1.w \
 + qv[8] * K2.x + qv[9] * K2.y + qv[10] * K2.z + qv[11] * K2.w \
 + qv[12] * K3.x + qv[13] * K3.y + qv[14] * K3.z + qv[15] * K3.w)

#define PVADD(av, wt, V0, V1, V2, V3) { \
  av[0] += (wt) * V0.x;  av[1] += (wt) * V0.y;  av[2] += (wt) * V0.z;  av[3] += (wt) * V0.w; \
  av[4] += (wt) * V1.x;  av[5] += (wt) * V1.y;  av[6] += (wt) * V1.z;  av[7] += (wt) * V1.w; \
  av[8] += (wt) * V2.x;  av[9] += (wt) * V2.y;  av[10] += (wt) * V2.z; av[11] += (wt) * V2.w; \
  av[12] += (wt) * V3.x; av[13] += (wt) * V3.y; av[14] += (wt) * V3.z; av[15] += (wt) * V3.w; }

__global__ __launch_bounds__(512) void k_mha(const float* __restrict__ kk,
                                             const float* __restrict__ vv,
                                             const float* __restrict__ qws,
                                             const unsigned int* __restrict__ mt32,
                                             float* __restrict__ part) {
  int bid = blockIdx.x;
  int swz = (bid & 7) * 128 + (bid >> 3);      // 16 blocks of same b per XCD
  int bh = swz >> 1, half = swz & 1;
  int b = bh >> 3;
  int tid = threadIdx.x;
  int w = tid >> 6;           // wave 0..7
  int lane = tid & 63;
  int p2 = lane + 64;
  int pc2 = p2 < PP ? p2 : PP - 1;

  __shared__ __align__(16) float smem_f[8192]; // 32 KB: k/v dbuf, then merge area
  float4* s4 = (float4*)smem_f;                // [buf][k 512 f4 | v 512 f4]

  float q1[QDQ], q2[QDQ];
  const float sc0 = 0.25f * LOG2E;
  {
    const float* qrow1 = qws + ((size_t)bh * PP + lane) * QDQ;
    const float* qrow2 = qws + ((size_t)bh * PP + pc2) * QDQ;
#pragma unroll
    for (int jj = 0; jj < QDQ; jj += 4) {
      float4 a4 = *(const float4*)(qrow1 + jj);
      q1[jj] = a4.x * sc0; q1[jj + 1] = a4.y * sc0;
      q1[jj + 2] = a4.z * sc0; q1[jj + 3] = a4.w * sc0;
      float4 b4 = *(const float4*)(qrow2 + jj);
      q2[jj] = b4.x * sc0; q2[jj + 1] = b4.y * sc0;
      q2[jj + 2] = b4.z * sc0; q2[jj + 3] = b4.w * sc0;
    }
  }

  float acc1[QDQ], acc2[QDQ];
#pragma unroll
  for (int jj = 0; jj < QDQ; ++jj) { acc1[jj] = 0.f; acc2[jj] = 0.f; }
  float l1 = 0.f, l2 = 0.f;

  const float4* kg4 = (const float4*)(kk + (size_t)bh * NTOT * QDQ);
  const float4* vg4 = (const float4*)(vv + (size_t)bh * NTOT * QDQ);
  int key0 = half * HALFK;
  int gbase = key0 * 4;
  int lim = NTOT * 4 - 1;

  float4 rk, rv;
  { int gi = gbase + tid; gi = gi < lim ? gi : lim; rk = kg4[gi]; rv = vg4[gi]; }

  int cur = 0;
  for (int c = 0; c < 5; ++c) {                // 598 = 4*128 + 86
    int base = c * CH;
    int L = HALFK - base; if (L > CH) L = CH;
    __syncthreads();
    s4[cur * 1024 + tid] = rk;
    s4[cur * 1024 + 512 + tid] = rv;
    __syncthreads();
    if (c < 4) {
      int gi = gbase + (c + 1) * 512 + tid; gi = gi < lim ? gi : lim;
      rk = kg4[gi]; rv = vg4[gi];
    }
    const unsigned int* mrow = mt32 + ((size_t)b * NTOT + key0 + base) * 64;
    int kb = cur * 1024, vb = cur * 1024 + 512;

    int i = w;
    for (; i + 8 < L; i += 16) {               // two keys per iteration
      unsigned int mma = mrow[i * 64 + lane];
      unsigned int mmb = mrow[(i + 8) * 64 + lane];
      float4 a0 = s4[kb + i * 4 + 0], a1 = s4[kb + i * 4 + 1];
      float4 a2 = s4[kb + i * 4 + 2], a3 = s4[kb + i * 4 + 3];
      float4 b0 = s4[kb + (i + 8) * 4 + 0], b1 = s4[kb + (i + 8) * 4 + 1];
      float4 b2 = s4[kb + (i + 8) * 4 + 2], b3 = s4[kb + (i + 8) * 4 + 3];
      float sa1 = QKDOT(q1, a0, a1, a2, a3);
      float sa2 = QKDOT(q2, a0, a1, a2, a3);
      float sb1 = QKDOT(q1, b0, b1, b2, b3);
      float sb2 = QKDOT(q2, b0, b1, b2, b3);
      float wa1 = exp2f(sa1 + __uint_as_float(mma << 16));
      float wa2 = exp2f(sa2 + __uint_as_float(mma & 0xffff0000u));
      float wb1 = exp2f(sb1 + __uint_as_float(mmb << 16));
      float wb2 = exp2f(sb2 + __uint_as_float(mmb & 0xffff0000u));
      l1 += wa1 + wb1; l2 += wa2 + wb2;
      float4 u0 = s4[vb + i * 4 + 0], u1 = s4[vb + i * 4 + 1];
      float4 u2 = s4[vb + i * 4 + 2], u3 = s4[vb + i * 4 + 3];
      PVADD(acc1, wa1, u0, u1, u2, u3)
      PVADD(acc2, wa2, u0, u1, u2, u3)
      float4 t0 = s4[vb + (i + 8) * 4 + 0], t1 = s4[vb + (i + 8) * 4 + 1];
      float4 t2 = s4[vb + (i + 8) * 4 + 2], t3 = s4[vb + (i + 8) * 4 + 3];
      PVADD(acc1, wb1, t0, t1, t2, t3)
      PVADD(acc2, wb2, t0, t1, t2, t3)
    }
    if (i < L) {                               // tail key
      unsigned int mma = mrow[i * 64 + lane];
      float4 a0 = s4[kb + i * 4 + 0], a1 = s4[kb + i * 4 + 1];
      float4 a2 = s4[kb + i * 4 + 2], a3 = s4[kb + i * 4 + 3];
      float sa1 = QKDOT(q1, a0, a1, a2, a3);
      float sa2 = QKDOT(q2, a0, a1, a2, a3);
      float wa1 = exp2f(sa1 + __uint_as_float(mma << 16));
      float wa2 = exp2f(sa2 + __uint_as_float(mma & 0xffff0000u));
      l1 += wa1; l2 += wa2;
      float4 u0 = s4[vb + i * 4 + 0], u1 = s4[vb + i * 4 + 1];
      float4 u2 = s4[vb + i * 4 + 2], u3 = s4[vb + i * 4 + 3];
      PVADD(acc1, wa1, u0, u1, u2, u3)
      PVADD(acc2, wa2, u0, u1, u2, u3)
    }
    cur ^= 1;
  }

  // ---- 8->1 merge (pure sums), 2-phase over 4-record LDS area [4][PP][17] ----
  __syncthreads();
  if (w < 4) {
    float* r = smem_f + ((size_t)w * PP + lane) * 17;
#pragma unroll
    for (int jj = 0; jj < QDQ; ++jj) r[jj] = acc1[jj];
    r[16] = l1;
    if (p2 < PP) {
      float* r2 = smem_f + ((size_t)w * PP + p2) * 17;
#pragma unroll
      for (int jj = 0; jj < QDQ; ++jj) r2[jj] = acc2[jj];
      r2[16] = l2;
    }
  }
  __syncthreads();
  if (w >= 4) {
    float* r = smem_f + ((size_t)(w - 4) * PP + lane) * 17;
#pragma unroll
    for (int jj = 0; jj < QDQ; ++jj) r[jj] += acc1[jj];
    r[16] += l1;
    if (p2 < PP) {
      float* r2 = smem_f + ((size_t)(w - 4) * PP + p2) * 17;
#pragma unroll
      for (int jj = 0; jj < QDQ; ++jj) r2[jj] += acc2[jj];
      r2[16] += l2;
    }
  }
  __syncthreads();
  for (int idx = tid; idx < PP * 17; idx += 512) {
    int pp2 = idx / 17, e = idx % 17;
    float vsum = smem_f[(0 * PP + pp2) * 17 + e] + smem_f[(1 * PP + pp2) * 17 + e]
               + smem_f[(2 * PP + pp2) * 17 + e] + smem_f[(3 * PP + pp2) * 17 + e];
    part[((size_t)swz * PP + pp2) * 17 + e] = vsum;
  }
}

// ---------------- Kernel C: merge 2 halves (sum) + mh_combine (LDS GEMM) ------
__global__ __launch_bounds__(256) void k_combine(const float* __restrict__ part,
                                                 const float* __restrict__ MC,
                                                 float* __restrict__ mh) {
  __shared__ float sw[128 * 65];       // MC[j][dl] current half, padded
  __shared__ float oc[QROWS * DD];     // 8 KB
  int tid = threadIdx.x;
  int row0 = blockIdx.x * QROWS;

  for (int i = tid; i < QROWS * DD; i += 256) {
    int r = i >> 7, t = i & 127;
    int bp = row0 + r, b = bp / PP, p = bp % PP;
    int qd = t & 15, h = t >> 4;
    int bh = b * HH + h;
    const float* r0 = part + (((size_t)(bh * 2 + 0)) * PP + p) * 17;
    const float* r1 = part + (((size_t)(bh * 2 + 1)) * PP + p) * 17;
    float A = r0[qd] + r1[qd];
    float L = r0[16] + r1[16];
    oc[i] = A / L;
  }

  int j = tid & 127, rr = tid >> 7;
  float acc[8];
#pragma unroll
  for (int i = 0; i < 8; ++i) acc[i] = 0.f;

  for (int half = 0; half < 2; ++half) {
    __syncthreads();
    for (int idx = tid; idx < 128 * 64; idx += 256) {
      int jj = idx >> 6, dl = idx & 63;
      sw[jj * 65 + dl] = MC[jj * DD + half * 64 + dl];
    }
    __syncthreads();
#pragma unroll
    for (int ri = 0; ri < 8; ++ri) {
      int r = 2 * ri + rr;
      float a = acc[ri];
#pragma unroll 16
      for (int dl = 0; dl < 64; ++dl)
        a += oc[r * DD + half * 64 + dl] * sw[j * 65 + dl];
      acc[ri] = a;
    }
  }
#pragma unroll
  for (int ri = 0; ri < 8; ++ri) {
    int bp = row0 + 2 * ri + rr;
    mh[(size_t)bp * DD + j] = acc[ri];
  }
}

// ---------------- Kernel D: score2[b,p,n] = sum_d mh[b,p,d]*shk[b,d,n] --------
__global__ __launch_bounds__(256) void k_score2(const float* __restrict__ mh,
                                                const float* __restrict__ shk,
                                                float* __restrict__ sc) {
  int bid = blockIdx.x;
  int swz = (bid & 7) * 128 + (bid >> 3);      // same-b blocks share an XCD
  int b = swz >> 4, nt = swz & 15;
  int tid = threadIdx.x; int nl = tid & 31, pg = tid >> 5;
  __shared__ float A[PP * 132];
  for (int idx = tid; idx < PP * DD; idx += 256)
    A[(idx >> 7) * 132 + (idx & 127)] = mh[(size_t)b * PP * DD + idx];
  __syncthreads();

  int na = nt * 64 + nl, nb2 = na + 32;
  int nca = na < NN ? na : NN - 1, ncb = nb2 < NN ? nb2 : NN - 1;
  const float* S = shk + (size_t)b * DD * NN;
  float acc0[13], acc1[13];
#pragma unroll
  for (int i = 0; i < 13; ++i) { acc0[i] = 0.f; acc1[i] = 0.f; }

  for (int d = 0; d < DD; d += 4) {
    float sa0 = S[(size_t)(d + 0) * NN + nca];
    float sa1 = S[(size_t)(d + 1) * NN + nca];
    float sa2 = S[(size_t)(d + 2) * NN + nca];
    float sa3 = S[(size_t)(d + 3) * NN + nca];
    float sb0 = S[(size_t)(d + 0) * NN + ncb];
    float sb1 = S[(size_t)(d + 1) * NN + ncb];
    float sb2 = S[(size_t)(d + 2) * NN + ncb];
    float sb3 = S[(size_t)(d + 3) * NN + ncb];
#pragma unroll
    for (int i = 0; i < 13; ++i) {
      int p = pg + (i << 3);
      if (p < PP) {
        const float4 a4 = *(const float4*)&A[p * 132 + d];
        acc0[i] += a4.x * sa0 + a4.y * sa1 + a4.z * sa2 + a4.w * sa3;
        acc1[i] += a4.x * sb0 + a4.y * sb1 + a4.z * sb2 + a4.w * sb3;
      }
    }
  }
#pragma unroll
  for (int i = 0; i < 13; ++i) {
    int p = pg + (i << 3);
    if (p < PP) {
      size_t base = ((size_t)b * PP + p) * NN;
      if (na < NN) sc[base + na] = acc0[i];
      if (nb2 < NN) sc[base + nb2] = acc1[i];
    }
  }
}

// ---------------- Kernel E: fast-tanh clip + edge bias + mask + row softmax ---
__global__ __launch_bounds__(256) void k_finsm(const float* __restrict__ sc,
                                               const float* __restrict__ eb,
                                               const int* __restrict__ cn,
                                               const float* __restrict__ mask,
                                               float* __restrict__ out) {
  int bid = blockIdx.x;
  int bp = (bid & 7) * 800 + (bid >> 3);       // XCD swizzle (6400 % 8 == 0)
  int b = bp / PP;
  int t = threadIdx.x;
  int node = cn[bp];
  const float* scp = sc + (size_t)bp * NN;
  const float* ebp = eb + ((size_t)b * NN + node) * NN;
  const float* mp = mask + (size_t)bp * NN;
  const float inv_sqrtD = 0.08838834764831845f;  // 1/sqrt(128)

  float vals[4];
  float m = -1e30f;
#pragma unroll
  for (int i = 0; i < 4; ++i) {
    int n = t + (i << 8);
    if (n < NN) {
      float z = scp[n] * inv_sqrtD;
      float e = __expf(2.f * z);
      float th10 = 10.f - 20.f * __builtin_amdgcn_rcpf(e + 1.f);  // 10*tanh(z)
      float lg = th10 + ebp[n] + mp[n];
      vals[i] = lg;
      m = fmaxf(m, lg);
    } else {
      vals[i] = -1e30f;
    }
  }
#pragma unroll
  for (int off = 32; off; off >>= 1) m = fmaxf(m, __shfl_xor(m, off));
  __shared__ float red[4];
  int w = t >> 6, lane = t & 63;
  if (lane == 0) red[w] = m;
  __syncthreads();
  m = fmaxf(fmaxf(red[0], red[1]), fmaxf(red[2], red[3]));
  __syncthreads();

  float s = 0.f;
#pragma unroll
  for (int i = 0; i < 4; ++i) {
    int n = t + (i << 8);
    float e = (n < NN) ? __expf(vals[i] - m) : 0.f;
    vals[i] = e;
    s += e;
  }
#pragma unroll
  for (int off = 32; off; off >>= 1) s += __shfl_xor(s, off);
  if (lane == 0) red[w] = s;
  __syncthreads();
  s = red[0] + red[1] + red[2] + red[3];
  float inv = 1.f / s;
#pragma unroll
  for (int i = 0; i < 4; ++i) {
    int n = t + (i << 8);
    if (n < NN) out[(size_t)bp * NN + n] = vals[i] * inv;
  }
}

extern "C" void kernel_launch(void* const* d_in, const int* in_sizes, int n_in,
                              void* d_out, int out_size, void* d_ws, size_t ws_size,
                              hipStream_t stream) {
  const float* x    = (const float*)d_in[0];   // encoded_last_node (B,P,D)
  const float* mask = (const float*)d_in[1];   // ninf_mask (B,P,N)
  const float* qf   = (const float*)d_in[2];   // q_first (B,H,P,QD)
  const float* kk   = (const float*)d_in[3];   // k (B,H,NTOT,QD)
  const float* vv   = (const float*)d_in[4];   // v (B,H,NTOT,QD)
  const float* shk  = (const float*)d_in[5];   // single_head_key (B,D,N)
  const float* Wq   = (const float*)d_in[6];   // (128,128)
  const float* MC   = (const float*)d_in[7];   // (128,128)
  const float* eb   = (const float*)d_in[8];   // edge_bias (B,N,N)
  const int*   cn   = (const int*)d_in[9];     // current_node (B,P)

  float* out = (float*)d_out;
  float* ws = (float*)d_ws;
  float* q_ws = ws;                            //   819,200 f
  float* part = ws + 819200;                   // 1,740,800 f (1024*100*17)
  float* mh   = ws + 2560000;                  //   819,200 f
  float* reg  = ws + 3379200;                  // 6,400,000 f shared region:
  __hip_bfloat16* mt = (__hip_bfloat16*)reg;   //   mt bf16 (9,797,632 ush = 4.9M f)
  float* sc   = reg;                           //   sc overlays mt (after last mt read)

  hipLaunchKernelGGL(k_qcalc, dim3(400), dim3(256), 0, stream, x, Wq, qf, q_ws);
  hipLaunchKernelGGL(k_mask_t, dim3(19, 2, BB), dim3(256), 0, stream, mask, mt);
  hipLaunchKernelGGL(k_mha, dim3(1024), dim3(512), 0, stream, kk, vv, q_ws,
                     (const unsigned int*)mt, part);
  hipLaunchKernelGGL(k_combine, dim3(400), dim3(256), 0, stream, part, MC, mh);
  hipLaunchKernelGGL(k_score2, dim3(1024), dim3(256), 0, stream, mh, shk, sc);
  hipLaunchKernelGGL(k_finsm, dim3(6400), dim3(256), 0, stream, sc, eb, cn, mask, out);
}

// Round 10
// 223.040 us; speedup vs baseline: 1.1175x; 1.1175x over previous
//
#include <hip/hip_runtime.h>
#include <hip/hip_bf16.h>
#include <math.h>

#define BB 64
#define PP 100
#define NN 1000
#define DD 128
#define HH 8
#define QDQ 16
#define NTOT 1196
#define HALFK 598
#define CH 128
#define QROWS 16
#define LOG2E 1.44269504088896f
#define EXP2(x) __builtin_amdgcn_exp2f(x)

// ------- Kernel P: fused {q = q_first + x @ Wq^T} and {mask -> bf16 table} ----
// blocks 0..399: qcalc (16 bp-rows each); blocks 400..2831: mask tiles.
__global__ __launch_bounds__(256) void k_prep(const float* __restrict__ x,
                                              const float* __restrict__ Wq,
                                              const float* __restrict__ qf,
                                              float* __restrict__ qout,
                                              const float* __restrict__ mask,
                                              __hip_bfloat16* __restrict__ mt) {
  __shared__ float sw[128 * 65];       // qcalc: W[j][dl] padded; mask: tile alias
  __shared__ float xs[QROWS * DD];
  int tid = threadIdx.x;

  if (blockIdx.x < 400) {
    int row0 = blockIdx.x * QROWS;
    for (int i = tid; i < QROWS * DD / 4; i += 256)
      ((float4*)xs)[i] = ((const float4*)(x + (size_t)row0 * DD))[i];

    int j = tid & 127, rr = tid >> 7;
    float acc[8];
#pragma unroll
    for (int i = 0; i < 8; ++i) acc[i] = 0.f;

    for (int half = 0; half < 2; ++half) {
      __syncthreads();
      for (int idx = tid; idx < 128 * 64; idx += 256) {
        int jj = idx >> 6, dl = idx & 63;
        sw[jj * 65 + dl] = Wq[jj * DD + half * 64 + dl];   // coalesced row reads
      }
      __syncthreads();
#pragma unroll
      for (int ri = 0; ri < 8; ++ri) {
        int r = 2 * ri + rr;
        float a = acc[ri];
#pragma unroll 16
        for (int dl = 0; dl < 64; ++dl)
          a += xs[r * DD + half * 64 + dl] * sw[j * 65 + dl];
        acc[ri] = a;
      }
    }
#pragma unroll
    for (int ri = 0; ri < 8; ++ri) {
      int bp = row0 + 2 * ri + rr;
      int b = bp / PP, p = bp % PP;
      int h = j >> 4, qd = j & 15;
      size_t qi = ((size_t)(b * HH + h) * PP + p) * QDQ + qd;
      qout[qi] = acc[ri] + qf[qi];
    }
  } else {
    // mask transpose+pad -> bf16 mt[b][n][p'] = mask*log2e - 20
    // p' pair-packs (p, p+64) into one dword: p' = 2*(p&63) | (p>>6)
    float (*tile)[65] = (float(*)[65])sw;
    int t = blockIdx.x - 400;
    int b = t / 38, rem = t % 38;
    int nt = rem % 19, pt = rem / 19;
    int tx = tid & 63, ty = tid >> 6;
    int n0 = nt * 64, p0 = pt * 64;
#pragma unroll
    for (int r = ty; r < 64; r += 4) {
      int p = p0 + r, n = n0 + tx;
      tile[r][tx] = (p < PP && n < NN) ? mask[((size_t)b * PP + p) * NN + n] * LOG2E - 20.f
                                       : -20.f;
    }
    __syncthreads();
#pragma unroll
    for (int r = ty; r < 64; r += 4) {
      int n = n0 + r, p = p0 + tx;
      int pp = ((p & 63) << 1) | (p >> 6);
      if (n < NTOT)
        mt[((size_t)b * NTOT + n) * 128 + pp] = __float2bfloat16(tile[tx][r]);
    }
  }
}

// ---------------- Kernel B: MHA partial — 2q/lane, bf16 mask, raw v_exp -------
// grid = 1024 (XCD-swizzled: 512 bh * 2 halves); block = 512 (8 waves)
// wave w handles keys {w, w+8, ...} of each 128-key chunk; lane owns queries
// (lane, lane+64). Fixed -20 offset baked into mt -> w = exp2(s), sums only.
#define QKDOT(qv, K0, K1, K2, K3) \
  (qv[0] * K0.x + qv[1] * K0.y + qv[2] * K0.z + qv[3] * K0.w \
 + qv[4] * K1.x + qv[5] * K1.y + qv[6] * K1.z + qv[7] * K1.w \
 + qv[8] * K2.x + qv[9] * K2.y + qv[10] * K2.z + qv[11] * K2.w \
 + qv[12] * K3.x + qv[13] * K3.y + qv[14] * K3.z + qv[15] * K3.w)

#define PVADD(av, wt, V0, V1, V2, V3) { \
  av[0] += (wt) * V0.x;  av[1] += (wt) * V0.y;  av[2] += (wt) * V0.z;  av[3] += (wt) * V0.w; \
  av[4] += (wt) * V1.x;  av[5] += (wt) * V1.y;  av[6] += (wt) * V1.z;  av[7] += (wt) * V1.w; \
  av[8] += (wt) * V2.x;  av[9] += (wt) * V2.y;  av[10] += (wt) * V2.z; av[11] += (wt) * V2.w; \
  av[12] += (wt) * V3.x; av[13] += (wt) * V3.y; av[14] += (wt) * V3.z; av[15] += (wt) * V3.w; }

__global__ __launch_bounds__(512) void k_mha(const float* __restrict__ kk,
                                             const float* __restrict__ vv,
                                             const float* __restrict__ qws,
                                             const unsigned int* __restrict__ mt32,
                                             float* __restrict__ part) {
  int bid = blockIdx.x;
  int swz = (bid & 7) * 128 + (bid >> 3);      // 16 blocks of same b per XCD
  int bh = swz >> 1, half = swz & 1;
  int b = bh >> 3;
  int tid = threadIdx.x;
  int w = tid >> 6;           // wave 0..7
  int lane = tid & 63;
  int p2 = lane + 64;
  int pc2 = p2 < PP ? p2 : PP - 1;

  __shared__ __align__(16) float smem_f[8192]; // 32 KB: k/v dbuf, then merge area
  float4* s4 = (float4*)smem_f;                // [buf][k 512 f4 | v 512 f4]

  float q1[QDQ], q2[QDQ];
  const float sc0 = 0.25f * LOG2E;
  {
    const float* qrow1 = qws + ((size_t)bh * PP + lane) * QDQ;
    const float* qrow2 = qws + ((size_t)bh * PP + pc2) * QDQ;
#pragma unroll
    for (int jj = 0; jj < QDQ; jj += 4) {
      float4 a4 = *(const float4*)(qrow1 + jj);
      q1[jj] = a4.x * sc0; q1[jj + 1] = a4.y * sc0;
      q1[jj + 2] = a4.z * sc0; q1[jj + 3] = a4.w * sc0;
      float4 b4 = *(const float4*)(qrow2 + jj);
      q2[jj] = b4.x * sc0; q2[jj + 1] = b4.y * sc0;
      q2[jj + 2] = b4.z * sc0; q2[jj + 3] = b4.w * sc0;
    }
  }

  float acc1[QDQ], acc2[QDQ];
#pragma unroll
  for (int jj = 0; jj < QDQ; ++jj) { acc1[jj] = 0.f; acc2[jj] = 0.f; }
  float l1 = 0.f, l2 = 0.f;

  const float4* kg4 = (const float4*)(kk + (size_t)bh * NTOT * QDQ);
  const float4* vg4 = (const float4*)(vv + (size_t)bh * NTOT * QDQ);
  int key0 = half * HALFK;
  int gbase = key0 * 4;
  int lim = NTOT * 4 - 1;

  float4 rk, rv;
  { int gi = gbase + tid; gi = gi < lim ? gi : lim; rk = kg4[gi]; rv = vg4[gi]; }

  int cur = 0;
  for (int c = 0; c < 5; ++c) {                // 598 = 4*128 + 86
    int base = c * CH;
    int L = HALFK - base; if (L > CH) L = CH;
    __syncthreads();
    s4[cur * 1024 + tid] = rk;
    s4[cur * 1024 + 512 + tid] = rv;
    __syncthreads();
    if (c < 4) {
      int gi = gbase + (c + 1) * 512 + tid; gi = gi < lim ? gi : lim;
      rk = kg4[gi]; rv = vg4[gi];
    }
    const unsigned int* mrow = mt32 + ((size_t)b * NTOT + key0 + base) * 64;
    int kb = cur * 1024, vb = cur * 1024 + 512;

    unsigned int nmm = mrow[w * 64 + lane];    // pipelined mask (1 key ahead)
    for (int i = w; i < L; i += 8) {
      unsigned int mm = nmm;
      int inx = i + 8; inx = inx < L ? inx : i;
      nmm = mrow[inx * 64 + lane];

      float4 k0 = s4[kb + i * 4 + 0], k1 = s4[kb + i * 4 + 1];
      float4 k2 = s4[kb + i * 4 + 2], k3 = s4[kb + i * 4 + 3];
      float s1 = QKDOT(q1, k0, k1, k2, k3);
      float s2 = QKDOT(q2, k0, k1, k2, k3);
      float w1 = EXP2(s1 + __uint_as_float(mm << 16));
      float w2 = EXP2(s2 + __uint_as_float(mm & 0xffff0000u));
      l1 += w1; l2 += w2;
      float4 v0 = s4[vb + i * 4 + 0], v1 = s4[vb + i * 4 + 1];
      float4 v2 = s4[vb + i * 4 + 2], v3 = s4[vb + i * 4 + 3];
      PVADD(acc1, w1, v0, v1, v2, v3)
      PVADD(acc2, w2, v0, v1, v2, v3)
    }
    cur ^= 1;
  }

  // ---- 8->1 merge (pure sums), 2-phase over 4-record LDS area [4][PP][17] ----
  __syncthreads();
  if (w < 4) {
    float* r = smem_f + ((size_t)w * PP + lane) * 17;
#pragma unroll
    for (int jj = 0; jj < QDQ; ++jj) r[jj] = acc1[jj];
    r[16] = l1;
    if (p2 < PP) {
      float* r2 = smem_f + ((size_t)w * PP + p2) * 17;
#pragma unroll
      for (int jj = 0; jj < QDQ; ++jj) r2[jj] = acc2[jj];
      r2[16] = l2;
    }
  }
  __syncthreads();
  if (w >= 4) {
    float* r = smem_f + ((size_t)(w - 4) * PP + lane) * 17;
#pragma unroll
    for (int jj = 0; jj < QDQ; ++jj) r[jj] += acc1[jj];
    r[16] += l1;
    if (p2 < PP) {
      float* r2 = smem_f + ((size_t)(w - 4) * PP + p2) * 17;
#pragma unroll
      for (int jj = 0; jj < QDQ; ++jj) r2[jj] += acc2[jj];
      r2[16] += l2;
    }
  }
  __syncthreads();
  for (int idx = tid; idx < PP * 17; idx += 512) {
    int pp2 = idx / 17, e = idx % 17;
    float vsum = smem_f[(0 * PP + pp2) * 17 + e] + smem_f[(1 * PP + pp2) * 17 + e]
               + smem_f[(2 * PP + pp2) * 17 + e] + smem_f[(3 * PP + pp2) * 17 + e];
    part[((size_t)swz * PP + pp2) * 17 + e] = vsum;
  }
}

// ---------------- Kernel C: merge 2 halves (sum) + mh_combine (LDS GEMM) ------
__global__ __launch_bounds__(256) void k_combine(const float* __restrict__ part,
                                                 const float* __restrict__ MC,
                                                 float* __restrict__ mh) {
  __shared__ float sw[128 * 65];       // MC[j][dl] current half, padded
  __shared__ float oc[QROWS * DD];
  int tid = threadIdx.x;
  int row0 = blockIdx.x * QROWS;

  for (int i = tid; i < QROWS * DD; i += 256) {
    int r = i >> 7, t = i & 127;
    int bp = row0 + r, b = bp / PP, p = bp % PP;
    int qd = t & 15, h = t >> 4;
    int bh = b * HH + h;
    const float* r0 = part + (((size_t)(bh * 2 + 0)) * PP + p) * 17;
    const float* r1 = part + (((size_t)(bh * 2 + 1)) * PP + p) * 17;
    float A = r0[qd] + r1[qd];
    float L = r0[16] + r1[16];
    oc[i] = A / L;
  }

  int j = tid & 127, rr = tid >> 7;
  float acc[8];
#pragma unroll
  for (int i = 0; i < 8; ++i) acc[i] = 0.f;

  for (int half = 0; half < 2; ++half) {
    __syncthreads();
    for (int idx = tid; idx < 128 * 64; idx += 256) {
      int jj = idx >> 6, dl = idx & 63;
      sw[jj * 65 + dl] = MC[jj * DD + half * 64 + dl];
    }
    __syncthreads();
#pragma unroll
    for (int ri = 0; ri < 8; ++ri) {
      int r = 2 * ri + rr;
      float a = acc[ri];
#pragma unroll 16
      for (int dl = 0; dl < 64; ++dl)
        a += oc[r * DD + half * 64 + dl] * sw[j * 65 + dl];
      acc[ri] = a;
    }
  }
#pragma unroll
  for (int ri = 0; ri < 8; ++ri) {
    int bp = row0 + 2 * ri + rr;
    mh[(size_t)bp * DD + j] = acc[ri];
  }
}

// ---------------- Kernel D: score2[b,p,n] = sum_d mh[b,p,d]*shk[b,d,n] --------
__global__ __launch_bounds__(256) void k_score2(const float* __restrict__ mh,
                                                const float* __restrict__ shk,
                                                float* __restrict__ sc) {
  int bid = blockIdx.x;
  int swz = (bid & 7) * 128 + (bid >> 3);      // same-b blocks share an XCD
  int b = swz >> 4, nt = swz & 15;
  int tid = threadIdx.x; int nl = tid & 31, pg = tid >> 5;
  __shared__ float A[PP * 132];
  for (int idx = tid; idx < PP * DD; idx += 256)
    A[(idx >> 7) * 132 + (idx & 127)] = mh[(size_t)b * PP * DD + idx];
  __syncthreads();

  int na = nt * 64 + nl, nb2 = na + 32;
  int nca = na < NN ? na : NN - 1, ncb = nb2 < NN ? nb2 : NN - 1;
  const float* S = shk + (size_t)b * DD * NN;
  float acc0[13], acc1[13];
#pragma unroll
  for (int i = 0; i < 13; ++i) { acc0[i] = 0.f; acc1[i] = 0.f; }

  for (int d = 0; d < DD; d += 4) {
    float sa0 = S[(size_t)(d + 0) * NN + nca];
    float sa1 = S[(size_t)(d + 1) * NN + nca];
    float sa2 = S[(size_t)(d + 2) * NN + nca];
    float sa3 = S[(size_t)(d + 3) * NN + nca];
    float sb0 = S[(size_t)(d + 0) * NN + ncb];
    float sb1 = S[(size_t)(d + 1) * NN + ncb];
    float sb2 = S[(size_t)(d + 2) * NN + ncb];
    float sb3 = S[(size_t)(d + 3) * NN + ncb];
#pragma unroll
    for (int i = 0; i < 13; ++i) {
      int p = pg + (i << 3);
      if (p < PP) {
        const float4 a4 = *(const float4*)&A[p * 132 + d];
        acc0[i] += a4.x * sa0 + a4.y * sa1 + a4.z * sa2 + a4.w * sa3;
        acc1[i] += a4.x * sb0 + a4.y * sb1 + a4.z * sb2 + a4.w * sb3;
      }
    }
  }
#pragma unroll
  for (int i = 0; i < 13; ++i) {
    int p = pg + (i << 3);
    if (p < PP) {
      size_t base = ((size_t)b * PP + p) * NN;
      if (na < NN) sc[base + na] = acc0[i];
      if (nb2 < NN) sc[base + nb2] = acc1[i];
    }
  }
}

// ---------------- Kernel E: fast-tanh clip + edge bias + mask + row softmax ---
__global__ __launch_bounds__(256) void k_finsm(const float* __restrict__ sc,
                                               const float* __restrict__ eb,
                                               const int* __restrict__ cn,
                                               const float* __restrict__ mask,
                                               float* __restrict__ out) {
  int bid = blockIdx.x;
  int bp = (bid & 7) * 800 + (bid >> 3);       // XCD swizzle (6400 % 8 == 0)
  int b = bp / PP;
  int t = threadIdx.x;
  int node = cn[bp];
  const float* scp = sc + (size_t)bp * NN;
  const float* ebp = eb + ((size_t)b * NN + node) * NN;
  const float* mp = mask + (size_t)bp * NN;
  const float inv_sqrtD = 0.08838834764831845f;  // 1/sqrt(128)

  float vals[4];
  float m = -1e30f;
#pragma unroll
  for (int i = 0; i < 4; ++i) {
    int n = t + (i << 8);
    if (n < NN) {
      float z = scp[n] * inv_sqrtD;
      float e = __expf(2.f * z);
      float th10 = 10.f - 20.f * __builtin_amdgcn_rcpf(e + 1.f);  // 10*tanh(z)
      float lg = th10 + ebp[n] + mp[n];
      vals[i] = lg;
      m = fmaxf(m, lg);
    } else {
      vals[i] = -1e30f;
    }
  }
#pragma unroll
  for (int off = 32; off; off >>= 1) m = fmaxf(m, __shfl_xor(m, off));
  __shared__ float red[4];
  int w = t >> 6, lane = t & 63;
  if (lane == 0) red[w] = m;
  __syncthreads();
  m = fmaxf(fmaxf(red[0], red[1]), fmaxf(red[2], red[3]));
  __syncthreads();

  float s = 0.f;
#pragma unroll
  for (int i = 0; i < 4; ++i) {
    int n = t + (i << 8);
    float e = (n < NN) ? __expf(vals[i] - m) : 0.f;
    vals[i] = e;
    s += e;
  }
#pragma unroll
  for (int off = 32; off; off >>= 1) s += __shfl_xor(s, off);
  if (lane == 0) red[w] = s;
  __syncthreads();
  s = red[0] + red[1] + red[2] + red[3];
  float inv = 1.f / s;
#pragma unroll
  for (int i = 0; i < 4; ++i) {
    int n = t + (i << 8);
    if (n < NN) out[(size_t)bp * NN + n] = vals[i] * inv;
  }
}

extern "C" void kernel_launch(void* const* d_in, const int* in_sizes, int n_in,
                              void* d_out, int out_size, void* d_ws, size_t ws_size,
                              hipStream_t stream) {
  const float* x    = (const float*)d_in[0];   // encoded_last_node (B,P,D)
  const float* mask = (const float*)d_in[1];   // ninf_mask (B,P,N)
  const float* qf   = (const float*)d_in[2];   // q_first (B,H,P,QD)
  const float* kk   = (const float*)d_in[3];   // k (B,H,NTOT,QD)
  const float* vv   = (const float*)d_in[4];   // v (B,H,NTOT,QD)
  const float* shk  = (const float*)d_in[5];   // single_head_key (B,D,N)
  const float* Wq   = (const float*)d_in[6];   // (128,128)
  const float* MC   = (const float*)d_in[7];   // (128,128)
  const float* eb   = (const float*)d_in[8];   // edge_bias (B,N,N)
  const int*   cn   = (const int*)d_in[9];     // current_node (B,P)

  float* out = (float*)d_out;
  float* ws = (float*)d_ws;
  float* q_ws = ws;                            //   819,200 f
  float* part = ws + 819200;                   // 1,740,800 f (1024*100*17)
  float* mh   = ws + 2560000;                  //   819,200 f
  float* reg  = ws + 3379200;                  // 6,400,000 f shared region:
  __hip_bfloat16* mt = (__hip_bfloat16*)reg;   //   mt bf16 (9,797,632 ush = 4.9M f)
  float* sc   = reg;                           //   sc overlays mt (after last mt read)

  hipLaunchKernelGGL(k_prep, dim3(2832), dim3(256), 0, stream, x, Wq, qf, q_ws, mask, mt);
  hipLaunchKernelGGL(k_mha, dim3(1024), dim3(512), 0, stream, kk, vv, q_ws,
                     (const unsigned int*)mt, part);
  hipLaunchKernelGGL(k_combine, dim3(400), dim3(256), 0, stream, part, MC, mh);
  hipLaunchKernelGGL(k_score2, dim3(1024), dim3(256), 0, stream, mh, shk, sc);
  hipLaunchKernelGGL(k_finsm, dim3(6400), dim3(256), 0, stream, sc, eb, cn, mask, out);
}